// Round 1
// baseline (793.923 us; speedup 1.0000x reference)
//
#include <hip/hip_runtime.h>

#define N_NODES 100000
#define N_EDGES 1600000
#define IN_FEAT 256
#define HID_F   128
#define OUT_FT  64

// ---------------- CSR build ----------------

__global__ void k_count(const int* __restrict__ dstA, int* __restrict__ counts) {
    int e = blockIdx.x * 256 + threadIdx.x;
    if (e < N_EDGES) atomicAdd(&counts[dstA[e]], 1);
}

__global__ void k_dinv(const int* __restrict__ counts, float* __restrict__ dinv) {
    int i = blockIdx.x * 256 + threadIdx.x;
    if (i < N_NODES) dinv[i] = rsqrtf((float)(counts[i] + 1));  // +1 self loop
}

__global__ __launch_bounds__(1024) void k_scan(const int* __restrict__ counts,
                                               int* __restrict__ offsets) {
    __shared__ int part[1024];
    const int CH = (N_NODES + 1023) / 1024;  // 98
    int t = threadIdx.x;
    int base = t * CH;
    int s = 0;
    for (int i = 0; i < CH; i++) {
        int idx = base + i;
        if (idx < N_NODES) s += counts[idx];
    }
    part[t] = s;
    __syncthreads();
    // Hillis-Steele inclusive scan over 1024 partials
    for (int off = 1; off < 1024; off <<= 1) {
        int v = (t >= off) ? part[t - off] : 0;
        __syncthreads();
        part[t] += v;
        __syncthreads();
    }
    int run = (t == 0) ? 0 : part[t - 1];  // exclusive prefix
    for (int i = 0; i < CH; i++) {
        int idx = base + i;
        if (idx < N_NODES) {
            offsets[idx] = run;
            run += counts[idx];
        }
    }
    if (t == 0) offsets[N_NODES] = N_EDGES;
}

__global__ void k_fill(const int* __restrict__ srcA, const int* __restrict__ dstA,
                       const int* __restrict__ offsets, int* __restrict__ fill,
                       int* __restrict__ csr) {
    int e = blockIdx.x * 256 + threadIdx.x;
    if (e < N_EDGES) {
        int d = dstA[e];
        int p = offsets[d] + atomicAdd(&fill[d], 1);
        csr[p] = srcA[e];
    }
}

// ---------------- fp32 tiled GEMM with dinv epilogue ----------------
// C[row][0..BN) = dinv[row] * sum_k A[row][k] * W[k][col]
// BM=128 rows/block, 256 threads = 16x16, thread tile 8 x TN.

template <int K, int BN, int TN>
__global__ __launch_bounds__(256) void k_gemm_scale(const float* __restrict__ A,
                                                    const float* __restrict__ W,
                                                    const float* __restrict__ dinv,
                                                    float* __restrict__ C) {
    const int BM = 128, KT = 32;
    __shared__ float xT[KT][BM + 4];  // k-major transposed x tile (+4 keeps f4 align)
    __shared__ float wt[KT][BN];
    int tid = threadIdx.x;
    int tx = tid & 15, ty = tid >> 4;
    int row0 = blockIdx.x * BM;

    float acc[8][TN];
#pragma unroll
    for (int i = 0; i < 8; i++)
#pragma unroll
        for (int j = 0; j < TN; j++) acc[i][j] = 0.f;

    for (int k0 = 0; k0 < K; k0 += KT) {
        // stage x tile (BM x KT) transposed: 1024 float4 loads, 4 per thread
#pragma unroll
        for (int j = 0; j < 4; j++) {
            int f = tid + j * 256;
            int r = f >> 3;
            int kq = (f & 7) * 4;
            int grow = row0 + r;
            float4 v = make_float4(0.f, 0.f, 0.f, 0.f);
            if (grow < N_NODES) v = *(const float4*)&A[(size_t)grow * K + k0 + kq];
            xT[kq + 0][r] = v.x;
            xT[kq + 1][r] = v.y;
            xT[kq + 2][r] = v.z;
            xT[kq + 3][r] = v.w;
        }
        // stage W tile (KT x BN), row-major, vector copy
#pragma unroll
        for (int j = 0; j < KT * BN / 1024; j++) {
            int f = tid + j * 256;
            int kk = f / (BN / 4);
            int c4 = (f % (BN / 4)) * 4;
            *(float4*)&wt[kk][c4] = *(const float4*)&W[(size_t)(k0 + kk) * BN + c4];
        }
        __syncthreads();
#pragma unroll
        for (int kk = 0; kk < KT; kk++) {
            float a[8], b[TN];
            *(float4*)&a[0] = *(const float4*)&xT[kk][ty * 8];
            *(float4*)&a[4] = *(const float4*)&xT[kk][ty * 8 + 4];
#pragma unroll
            for (int j = 0; j < TN; j += 4)
                *(float4*)&b[j] = *(const float4*)&wt[kk][tx * TN + j];
#pragma unroll
            for (int i = 0; i < 8; i++)
#pragma unroll
                for (int j = 0; j < TN; j++) acc[i][j] += a[i] * b[j];
        }
        __syncthreads();
    }
#pragma unroll
    for (int i = 0; i < 8; i++) {
        int grow = row0 + ty * 8 + i;
        if (grow < N_NODES) {
            float dv = dinv[grow];
#pragma unroll
            for (int j = 0; j < TN; j += 4) {
                float4 o;
                o.x = acc[i][j + 0] * dv;
                o.y = acc[i][j + 1] * dv;
                o.z = acc[i][j + 2] * dv;
                o.w = acc[i][j + 3] * dv;
                *(float4*)&C[(size_t)grow * BN + tx * TN + j] = o;
            }
        }
    }
}

// ---------------- aggregation (CSR gather-reduce) ----------------
// layer1: a1[i] = relu(dinv[i]*(sum_{s in csr[i]} hs[s] + hs[i]) + b)  (128 feats, float2/lane)

__global__ __launch_bounds__(256) void k_agg1(const float* __restrict__ hs,
                                              const int* __restrict__ offsets,
                                              const int* __restrict__ csr,
                                              const float* __restrict__ dinv,
                                              const float* __restrict__ b,
                                              float* __restrict__ out) {
    int wave = threadIdx.x >> 6;
    int lane = threadIdx.x & 63;
    int node = blockIdx.x * 4 + wave;
    if (node >= N_NODES) return;
    int beg = offsets[node], end = offsets[node + 1];
    float2 acc = *(const float2*)&hs[(size_t)node * HID_F + lane * 2];  // self loop
    int j = beg;
    for (; j + 4 <= end; j += 4) {
        int s0 = csr[j], s1 = csr[j + 1], s2 = csr[j + 2], s3 = csr[j + 3];
        float2 v0 = *(const float2*)&hs[(size_t)s0 * HID_F + lane * 2];
        float2 v1 = *(const float2*)&hs[(size_t)s1 * HID_F + lane * 2];
        float2 v2 = *(const float2*)&hs[(size_t)s2 * HID_F + lane * 2];
        float2 v3 = *(const float2*)&hs[(size_t)s3 * HID_F + lane * 2];
        acc.x += v0.x + v1.x + v2.x + v3.x;
        acc.y += v0.y + v1.y + v2.y + v3.y;
    }
    for (; j < end; j++) {
        int s = csr[j];
        float2 v = *(const float2*)&hs[(size_t)s * HID_F + lane * 2];
        acc.x += v.x;
        acc.y += v.y;
    }
    float dv = dinv[node];
    float2 bb = *(const float2*)&b[lane * 2];
    float2 o;
    o.x = fmaxf(dv * acc.x + bb.x, 0.f);
    o.y = fmaxf(dv * acc.y + bb.y, 0.f);
    *(float2*)&out[(size_t)node * HID_F + lane * 2] = o;
}

// layer2: out[i] = dinv[i]*(sum hs2[s] + hs2[i]) + b2   (64 feats, 1 float/lane, no relu)

__global__ __launch_bounds__(256) void k_agg2(const float* __restrict__ hs,
                                              const int* __restrict__ offsets,
                                              const int* __restrict__ csr,
                                              const float* __restrict__ dinv,
                                              const float* __restrict__ b,
                                              float* __restrict__ out) {
    int wave = threadIdx.x >> 6;
    int lane = threadIdx.x & 63;
    int node = blockIdx.x * 4 + wave;
    if (node >= N_NODES) return;
    int beg = offsets[node], end = offsets[node + 1];
    float acc = hs[(size_t)node * OUT_FT + lane];  // self loop
    int j = beg;
    for (; j + 4 <= end; j += 4) {
        int s0 = csr[j], s1 = csr[j + 1], s2 = csr[j + 2], s3 = csr[j + 3];
        acc += hs[(size_t)s0 * OUT_FT + lane] + hs[(size_t)s1 * OUT_FT + lane] +
               hs[(size_t)s2 * OUT_FT + lane] + hs[(size_t)s3 * OUT_FT + lane];
    }
    for (; j < end; j++) acc += hs[(size_t)csr[j] * OUT_FT + lane];
    out[(size_t)node * OUT_FT + lane] = dinv[node] * acc + b[lane];
}

// ---------------- launch ----------------

extern "C" void kernel_launch(void* const* d_in, const int* in_sizes, int n_in,
                              void* d_out, int out_size, void* d_ws, size_t ws_size,
                              hipStream_t stream) {
    const float* x  = (const float*)d_in[0];
    const int*   ei = (const int*)d_in[1];  // [2][E]
    const float* W1 = (const float*)d_in[2];
    const float* b1 = (const float*)d_in[3];
    const float* W2 = (const float*)d_in[4];
    const float* b2 = (const float*)d_in[5];
    float* out = (float*)d_out;

    char* ws = (char*)d_ws;
    int*   counts  = (int*)(ws + 0);            // N ints
    int*   offsets = (int*)(ws + 400384);       // N+1 ints
    int*   fill    = (int*)(ws + 800768);       // N ints
    float* dinv    = (float*)(ws + 1201152);    // N floats
    int*   csr     = (int*)(ws + 1601536);      // E ints
    float* hs1     = (float*)(ws + 8001536);    // N*128 floats
    float* a1      = (float*)(ws + 59201536);   // N*128 floats
    float* hs2     = hs1;                       // reuse: hs1 dead after agg1

    const int* srcA = ei;             // edge_index[0]
    const int* dstA = ei + N_EDGES;   // edge_index[1]

    hipMemsetAsync(counts, 0, N_NODES * sizeof(int), stream);
    hipMemsetAsync(fill, 0, N_NODES * sizeof(int), stream);

    k_count<<<(N_EDGES + 255) / 256, 256, 0, stream>>>(dstA, counts);
    k_dinv<<<(N_NODES + 255) / 256, 256, 0, stream>>>(counts, dinv);
    k_scan<<<1, 1024, 0, stream>>>(counts, offsets);
    k_fill<<<(N_EDGES + 255) / 256, 256, 0, stream>>>(srcA, dstA, offsets, fill, csr);

    // layer 1: hs1 = (x @ W1) * dinv ; a1 = relu(dinv*agg(hs1) + b1)
    k_gemm_scale<IN_FEAT, HID_F, 8><<<(N_NODES + 127) / 128, 256, 0, stream>>>(x, W1, dinv, hs1);
    k_agg1<<<(N_NODES + 3) / 4, 256, 0, stream>>>(hs1, offsets, csr, dinv, b1, a1);

    // layer 2: hs2 = (a1 @ W2) * dinv ; out = dinv*agg(hs2) + b2
    k_gemm_scale<HID_F, OUT_FT, 4><<<(N_NODES + 127) / 128, 256, 0, stream>>>(a1, W2, dinv, hs2);
    k_agg2<<<(N_NODES + 3) / 4, 256, 0, stream>>>(hs2, offsets, csr, dinv, b2, out);
}

// Round 2
// 615.316 us; speedup vs baseline: 1.2903x; 1.2903x over previous
//
#include <hip/hip_runtime.h>

#define N_NODES 100000
#define N_EDGES 1600000
#define IN_FEAT 256
#define HID_F   128
#define OUT_FT  64
#define NBLK_SCAN ((N_NODES + 255) / 256)  // 391

// ---------------- CSR build ----------------

__global__ void k_count(const int* __restrict__ dstA, int* __restrict__ counts) {
    int e = blockIdx.x * 256 + threadIdx.x;
    if (e < N_EDGES) atomicAdd(&counts[dstA[e]], 1);
}

__global__ void k_dinv(const int* __restrict__ counts, float* __restrict__ dinv) {
    int i = blockIdx.x * 256 + threadIdx.x;
    if (i < N_NODES) dinv[i] = rsqrtf((float)(counts[i] + 1));  // +1 self loop
}

// hierarchical scan: block sums -> scan of sums -> per-block offsets
__global__ __launch_bounds__(256) void k_blocksum(const int* __restrict__ counts,
                                                  int* __restrict__ blksum) {
    int i = blockIdx.x * 256 + threadIdx.x;
    int v = (i < N_NODES) ? counts[i] : 0;
#pragma unroll
    for (int o = 32; o > 0; o >>= 1) v += __shfl_down(v, o, 64);
    __shared__ int wsum[4];
    if ((threadIdx.x & 63) == 0) wsum[threadIdx.x >> 6] = v;
    __syncthreads();
    if (threadIdx.x == 0) blksum[blockIdx.x] = wsum[0] + wsum[1] + wsum[2] + wsum[3];
}

__global__ __launch_bounds__(512) void k_scanblk(const int* __restrict__ blksum,
                                                 int* __restrict__ blkoff) {
    __shared__ int sm[512];
    int t = threadIdx.x;
    int v = (t < NBLK_SCAN) ? blksum[t] : 0;
    sm[t] = v;
    __syncthreads();
    for (int o = 1; o < 512; o <<= 1) {
        int u = (t >= o) ? sm[t - o] : 0;
        __syncthreads();
        sm[t] += u;
        __syncthreads();
    }
    if (t < NBLK_SCAN) blkoff[t] = sm[t] - v;  // exclusive prefix of block sums
}

__global__ __launch_bounds__(256) void k_offsets(const int* __restrict__ counts,
                                                 const int* __restrict__ blkoff,
                                                 int* __restrict__ offsets) {
    __shared__ int sm[256];
    int t = threadIdx.x;
    int i = blockIdx.x * 256 + t;
    int v = (i < N_NODES) ? counts[i] : 0;
    sm[t] = v;
    __syncthreads();
    for (int o = 1; o < 256; o <<= 1) {
        int u = (t >= o) ? sm[t - o] : 0;
        __syncthreads();
        sm[t] += u;
        __syncthreads();
    }
    if (i < N_NODES) offsets[i] = blkoff[blockIdx.x] + sm[t] - v;
    if (i == N_NODES - 1) offsets[N_NODES] = N_EDGES;
}

__global__ void k_fill(const int* __restrict__ srcA, const int* __restrict__ dstA,
                       const int* __restrict__ offsets, int* __restrict__ fill,
                       int* __restrict__ csr) {
    int e = blockIdx.x * 256 + threadIdx.x;
    if (e < N_EDGES) {
        int d = dstA[e];
        int p = offsets[d] + atomicAdd(&fill[d], 1);
        csr[p] = srcA[e];
    }
}

// ---------------- fp32 tiled GEMM with dinv epilogue ----------------
// C[row][0..BN) = dinv[row] * sum_k A[row][k] * W[k][col]

template <int K, int BN, int TN>
__global__ __launch_bounds__(256) void k_gemm_scale(const float* __restrict__ A,
                                                    const float* __restrict__ W,
                                                    const float* __restrict__ dinv,
                                                    float* __restrict__ C) {
    const int BM = 128, KT = 32;
    __shared__ float xT[KT][BM + 4];
    __shared__ float wt[KT][BN];
    int tid = threadIdx.x;
    int tx = tid & 15, ty = tid >> 4;
    int row0 = blockIdx.x * BM;

    float acc[8][TN];
#pragma unroll
    for (int i = 0; i < 8; i++)
#pragma unroll
        for (int j = 0; j < TN; j++) acc[i][j] = 0.f;

    for (int k0 = 0; k0 < K; k0 += KT) {
#pragma unroll
        for (int j = 0; j < 4; j++) {
            int f = tid + j * 256;
            int r = f >> 3;
            int kq = (f & 7) * 4;
            int grow = row0 + r;
            float4 v = make_float4(0.f, 0.f, 0.f, 0.f);
            if (grow < N_NODES) v = *(const float4*)&A[(size_t)grow * K + k0 + kq];
            xT[kq + 0][r] = v.x;
            xT[kq + 1][r] = v.y;
            xT[kq + 2][r] = v.z;
            xT[kq + 3][r] = v.w;
        }
#pragma unroll
        for (int j = 0; j < KT * BN / 1024; j++) {
            int f = tid + j * 256;
            int kk = f / (BN / 4);
            int c4 = (f % (BN / 4)) * 4;
            *(float4*)&wt[kk][c4] = *(const float4*)&W[(size_t)(k0 + kk) * BN + c4];
        }
        __syncthreads();
#pragma unroll
        for (int kk = 0; kk < KT; kk++) {
            float a[8], b[TN];
            *(float4*)&a[0] = *(const float4*)&xT[kk][ty * 8];
            *(float4*)&a[4] = *(const float4*)&xT[kk][ty * 8 + 4];
#pragma unroll
            for (int j = 0; j < TN; j += 4)
                *(float4*)&b[j] = *(const float4*)&wt[kk][tx * TN + j];
#pragma unroll
            for (int i = 0; i < 8; i++)
#pragma unroll
                for (int j = 0; j < TN; j++) acc[i][j] += a[i] * b[j];
        }
        __syncthreads();
    }
#pragma unroll
    for (int i = 0; i < 8; i++) {
        int grow = row0 + ty * 8 + i;
        if (grow < N_NODES) {
            float dv = dinv[grow];
#pragma unroll
            for (int j = 0; j < TN; j += 4) {
                float4 o;
                o.x = acc[i][j + 0] * dv;
                o.y = acc[i][j + 1] * dv;
                o.z = acc[i][j + 2] * dv;
                o.w = acc[i][j + 3] * dv;
                *(float4*)&C[(size_t)grow * BN + tx * TN + j] = o;
            }
        }
    }
}

// ---------------- aggregation (CSR gather-reduce) ----------------

__global__ __launch_bounds__(256) void k_agg1(const float* __restrict__ hs,
                                              const int* __restrict__ offsets,
                                              const int* __restrict__ csr,
                                              const float* __restrict__ dinv,
                                              const float* __restrict__ b,
                                              float* __restrict__ out) {
    int wave = threadIdx.x >> 6;
    int lane = threadIdx.x & 63;
    int node = blockIdx.x * 4 + wave;
    if (node >= N_NODES) return;
    int beg = offsets[node], end = offsets[node + 1];
    float2 acc = *(const float2*)&hs[(size_t)node * HID_F + lane * 2];  // self loop
    int j = beg;
    for (; j + 4 <= end; j += 4) {
        int s0 = csr[j], s1 = csr[j + 1], s2 = csr[j + 2], s3 = csr[j + 3];
        float2 v0 = *(const float2*)&hs[(size_t)s0 * HID_F + lane * 2];
        float2 v1 = *(const float2*)&hs[(size_t)s1 * HID_F + lane * 2];
        float2 v2 = *(const float2*)&hs[(size_t)s2 * HID_F + lane * 2];
        float2 v3 = *(const float2*)&hs[(size_t)s3 * HID_F + lane * 2];
        acc.x += v0.x + v1.x + v2.x + v3.x;
        acc.y += v0.y + v1.y + v2.y + v3.y;
    }
    for (; j < end; j++) {
        int s = csr[j];
        float2 v = *(const float2*)&hs[(size_t)s * HID_F + lane * 2];
        acc.x += v.x;
        acc.y += v.y;
    }
    float dv = dinv[node];
    float2 bb = *(const float2*)&b[lane * 2];
    float2 o;
    o.x = fmaxf(dv * acc.x + bb.x, 0.f);
    o.y = fmaxf(dv * acc.y + bb.y, 0.f);
    *(float2*)&out[(size_t)node * HID_F + lane * 2] = o;
}

__global__ __launch_bounds__(256) void k_agg2(const float* __restrict__ hs,
                                              const int* __restrict__ offsets,
                                              const int* __restrict__ csr,
                                              const float* __restrict__ dinv,
                                              const float* __restrict__ b,
                                              float* __restrict__ out) {
    int wave = threadIdx.x >> 6;
    int lane = threadIdx.x & 63;
    int node = blockIdx.x * 4 + wave;
    if (node >= N_NODES) return;
    int beg = offsets[node], end = offsets[node + 1];
    float acc = hs[(size_t)node * OUT_FT + lane];  // self loop
    int j = beg;
    for (; j + 4 <= end; j += 4) {
        int s0 = csr[j], s1 = csr[j + 1], s2 = csr[j + 2], s3 = csr[j + 3];
        acc += hs[(size_t)s0 * OUT_FT + lane] + hs[(size_t)s1 * OUT_FT + lane] +
               hs[(size_t)s2 * OUT_FT + lane] + hs[(size_t)s3 * OUT_FT + lane];
    }
    for (; j < end; j++) acc += hs[(size_t)csr[j] * OUT_FT + lane];
    out[(size_t)node * OUT_FT + lane] = dinv[node] * acc + b[lane];
}

// ---------------- launch ----------------

extern "C" void kernel_launch(void* const* d_in, const int* in_sizes, int n_in,
                              void* d_out, int out_size, void* d_ws, size_t ws_size,
                              hipStream_t stream) {
    const float* x  = (const float*)d_in[0];
    const int*   ei = (const int*)d_in[1];  // [2][E]
    const float* W1 = (const float*)d_in[2];
    const float* b1 = (const float*)d_in[3];
    const float* W2 = (const float*)d_in[4];
    const float* b2 = (const float*)d_in[5];
    float* out = (float*)d_out;

    char* ws = (char*)d_ws;
    int*   counts  = (int*)(ws + 0);            // N ints
    int*   offsets = (int*)(ws + 400384);       // N+1 ints
    int*   fill    = (int*)(ws + 800768);       // N ints
    float* dinv    = (float*)(ws + 1201152);    // N floats
    int*   csr     = (int*)(ws + 1601536);      // E ints -> ends 8001536
    float* hs1     = (float*)(ws + 8001536);    // N*128 floats -> ends 59201536
    float* a1      = (float*)(ws + 59201536);   // N*128 floats
    float* hs2     = hs1;                       // reuse: hs1 dead after agg1
    // scan scratch lives in the (currently dead) hs1 region
    int*   blksum  = (int*)(ws + 8001536);
    int*   blkoff  = (int*)(ws + 8001536 + 4096);

    const int* srcA = ei;             // edge_index[0]
    const int* dstA = ei + N_EDGES;   // edge_index[1]

    hipMemsetAsync(counts, 0, N_NODES * sizeof(int), stream);
    hipMemsetAsync(fill, 0, N_NODES * sizeof(int), stream);

    k_count<<<(N_EDGES + 255) / 256, 256, 0, stream>>>(dstA, counts);
    k_dinv<<<(N_NODES + 255) / 256, 256, 0, stream>>>(counts, dinv);
    k_blocksum<<<NBLK_SCAN, 256, 0, stream>>>(counts, blksum);
    k_scanblk<<<1, 512, 0, stream>>>(blksum, blkoff);
    k_offsets<<<NBLK_SCAN, 256, 0, stream>>>(counts, blkoff, offsets);
    k_fill<<<(N_EDGES + 255) / 256, 256, 0, stream>>>(srcA, dstA, offsets, fill, csr);

    // layer 1: hs1 = (x @ W1) * dinv ; a1 = relu(dinv*agg(hs1) + b1)
    k_gemm_scale<IN_FEAT, HID_F, 8><<<(N_NODES + 127) / 128, 256, 0, stream>>>(x, W1, dinv, hs1);
    k_agg1<<<(N_NODES + 3) / 4, 256, 0, stream>>>(hs1, offsets, csr, dinv, b1, a1);

    // layer 2: hs2 = (a1 @ W2) * dinv ; out = dinv*agg(hs2) + b2
    k_gemm_scale<HID_F, OUT_FT, 4><<<(N_NODES + 127) / 128, 256, 0, stream>>>(a1, W2, dinv, hs2);
    k_agg2<<<(N_NODES + 3) / 4, 256, 0, stream>>>(hs2, offsets, csr, dinv, b2, out);
}

// Round 3
// 489.015 us; speedup vs baseline: 1.6235x; 1.2583x over previous
//
#include <hip/hip_runtime.h>
#include <hip/hip_bf16.h>

#define N_NODES 100000
#define N_EDGES 1600000
#define IN_FEAT 256
#define HID_F   128
#define OUT_FT  64
#define NBLK_SCAN ((N_NODES + 255) / 256)  // 391

typedef unsigned short u16;
typedef __attribute__((ext_vector_type(8))) unsigned short u16x8;
typedef __attribute__((ext_vector_type(8))) short short8;
typedef __attribute__((ext_vector_type(4))) float f32x4;

static __device__ inline u16 f2bf(float f) {
    __hip_bfloat16 h = __float2bfloat16(f);
    return *reinterpret_cast<u16*>(&h);
}

// ---------------- CSR build ----------------

__global__ void k_count(const int* __restrict__ dstA, int* __restrict__ counts) {
    int e = blockIdx.x * 256 + threadIdx.x;
    if (e < N_EDGES) atomicAdd(&counts[dstA[e]], 1);
}

__global__ void k_dinv(const int* __restrict__ counts, float* __restrict__ dinv) {
    int i = blockIdx.x * 256 + threadIdx.x;
    if (i < N_NODES) dinv[i] = rsqrtf((float)(counts[i] + 1));  // +1 self loop
}

__global__ __launch_bounds__(256) void k_blocksum(const int* __restrict__ counts,
                                                  int* __restrict__ blksum) {
    int i = blockIdx.x * 256 + threadIdx.x;
    int v = (i < N_NODES) ? counts[i] : 0;
#pragma unroll
    for (int o = 32; o > 0; o >>= 1) v += __shfl_down(v, o, 64);
    __shared__ int wsum[4];
    if ((threadIdx.x & 63) == 0) wsum[threadIdx.x >> 6] = v;
    __syncthreads();
    if (threadIdx.x == 0) blksum[blockIdx.x] = wsum[0] + wsum[1] + wsum[2] + wsum[3];
}

__global__ __launch_bounds__(512) void k_scanblk(const int* __restrict__ blksum,
                                                 int* __restrict__ blkoff) {
    __shared__ int sm[512];
    int t = threadIdx.x;
    int v = (t < NBLK_SCAN) ? blksum[t] : 0;
    sm[t] = v;
    __syncthreads();
    for (int o = 1; o < 512; o <<= 1) {
        int u = (t >= o) ? sm[t - o] : 0;
        __syncthreads();
        sm[t] += u;
        __syncthreads();
    }
    if (t < NBLK_SCAN) blkoff[t] = sm[t] - v;
}

__global__ __launch_bounds__(256) void k_offsets(const int* __restrict__ counts,
                                                 const int* __restrict__ blkoff,
                                                 int* __restrict__ offsets) {
    __shared__ int sm[256];
    int t = threadIdx.x;
    int i = blockIdx.x * 256 + t;
    int v = (i < N_NODES) ? counts[i] : 0;
    sm[t] = v;
    __syncthreads();
    for (int o = 1; o < 256; o <<= 1) {
        int u = (t >= o) ? sm[t - o] : 0;
        __syncthreads();
        sm[t] += u;
        __syncthreads();
    }
    if (i < N_NODES) offsets[i] = blkoff[blockIdx.x] + sm[t] - v;
    if (i == N_NODES - 1) offsets[N_NODES] = N_EDGES;
}

__global__ void k_fill(const int* __restrict__ srcA, const int* __restrict__ dstA,
                       const int* __restrict__ offsets, int* __restrict__ fill,
                       int* __restrict__ csr) {
    int e = blockIdx.x * 256 + threadIdx.x;
    if (e < N_EDGES) {
        int d = dstA[e];
        int p = offsets[d] + atomicAdd(&fill[d], 1);
        csr[p] = srcA[e];
    }
}

// W [K][N] fp32 -> Wt [N][K] bf16
__global__ void k_castT(const float* __restrict__ W, u16* __restrict__ Wt, int K, int N) {
    int idx = blockIdx.x * 256 + threadIdx.x;
    if (idx < K * N) {
        int k = idx / N, n = idx % N;
        Wt[n * K + k] = f2bf(W[idx]);
    }
}

// ---------------- MFMA bf16 GEMM, layer 1 ----------------
// hs1[r][c] = bf16( dinv[r] * sum_k x[r][k]*W1[k][c] ), K=256, N=128

__global__ __launch_bounds__(256) void k_gemm1(const float* __restrict__ A,
                                               const u16* __restrict__ Bt,   // W1t [128][256]
                                               const float* __restrict__ dinv,
                                               u16* __restrict__ C) {        // hs1 [N][128]
    __shared__ u16 As[128][40];  // stride 40 (80B = 20 words): 2-way-free bank pattern
    __shared__ u16 Bs[128][40];
    int tid = threadIdx.x;
    int wv = tid >> 6, lane = tid & 63;
    int m16 = lane & 15, quad = lane >> 4;
    int row0 = blockIdx.x * 128;
    int r = tid >> 1, h = tid & 1;  // staging coords: row r, 16-elem half h
    int grow_s = row0 + r;
    bool rok = grow_s < N_NODES;

    f32x4 acc[2][8];
#pragma unroll
    for (int i = 0; i < 2; i++)
#pragma unroll
        for (int j = 0; j < 8; j++) acc[i][j] = (f32x4)(0.f);

    for (int k0 = 0; k0 < IN_FEAT; k0 += 32) {
        // stage A (fp32 -> bf16): 16 floats/thread
        f32x4 v0 = (f32x4)(0.f), v1 = v0, v2 = v0, v3 = v0;
        if (rok) {
            const f32x4* src = (const f32x4*)&A[(size_t)grow_s * IN_FEAT + k0 + h * 16];
            v0 = src[0]; v1 = src[1]; v2 = src[2]; v3 = src[3];
        }
        u16x8 p0, p1;
#pragma unroll
        for (int j = 0; j < 4; j++) {
            p0[j] = f2bf(v0[j]); p0[4 + j] = f2bf(v1[j]);
            p1[j] = f2bf(v2[j]); p1[4 + j] = f2bf(v3[j]);
        }
        *(u16x8*)&As[r][h * 16] = p0;
        *(u16x8*)&As[r][h * 16 + 8] = p1;
        // stage Bt (copy bf16): row r = col n of W1
        const u16x8* bsrc = (const u16x8*)&Bt[(size_t)r * IN_FEAT + k0 + h * 16];
        *(u16x8*)&Bs[r][h * 16] = bsrc[0];
        *(u16x8*)&Bs[r][h * 16 + 8] = bsrc[1];
        __syncthreads();

        short8 af0 = *(const short8*)&As[32 * wv + m16][quad * 8];
        short8 af1 = *(const short8*)&As[32 * wv + 16 + m16][quad * 8];
#pragma unroll
        for (int ct = 0; ct < 8; ct++) {
            short8 bf = *(const short8*)&Bs[16 * ct + m16][quad * 8];
            acc[0][ct] = __builtin_amdgcn_mfma_f32_16x16x32_bf16(af0, bf, acc[0][ct], 0, 0, 0);
            acc[1][ct] = __builtin_amdgcn_mfma_f32_16x16x32_bf16(af1, bf, acc[1][ct], 0, 0, 0);
        }
        __syncthreads();
    }
#pragma unroll
    for (int rt = 0; rt < 2; rt++)
#pragma unroll
        for (int r4 = 0; r4 < 4; r4++) {
            int grow = row0 + 32 * wv + 16 * rt + quad * 4 + r4;
            if (grow < N_NODES) {
                float dv = dinv[grow];
#pragma unroll
                for (int ct = 0; ct < 8; ct++)
                    C[(size_t)grow * HID_F + 16 * ct + m16] = f2bf(acc[rt][ct][r4] * dv);
            }
        }
}

// ---------------- MFMA bf16 GEMM, layer 2 ----------------
// hs2[r][c] = bf16( dinv[r] * sum_k a1[r][k]*W2[k][c] ), K=128, N=64

__global__ __launch_bounds__(256) void k_gemm2(const u16* __restrict__ A,    // a1 [N][128]
                                               const u16* __restrict__ Bt,   // W2t [64][128]
                                               const float* __restrict__ dinv,
                                               u16* __restrict__ C) {        // hs2 [N][64]
    __shared__ u16 As[128][40];
    __shared__ u16 Bs[64][40];
    int tid = threadIdx.x;
    int wv = tid >> 6, lane = tid & 63;
    int m16 = lane & 15, quad = lane >> 4;
    int row0 = blockIdx.x * 128;
    int r = tid >> 1, h = tid & 1;
    int grow_s = row0 + r;
    bool rok = grow_s < N_NODES;
    int nb = tid >> 2, q = tid & 3;  // Bt staging

    f32x4 acc[2][4];
#pragma unroll
    for (int i = 0; i < 2; i++)
#pragma unroll
        for (int j = 0; j < 4; j++) acc[i][j] = (f32x4)(0.f);

    for (int k0 = 0; k0 < HID_F; k0 += 32) {
        u16x8 a0 = (u16x8)(0), a1v = (u16x8)(0);
        if (rok) {
            const u16x8* src = (const u16x8*)&A[(size_t)grow_s * HID_F + k0 + h * 16];
            a0 = src[0]; a1v = src[1];
        }
        *(u16x8*)&As[r][h * 16] = a0;
        *(u16x8*)&As[r][h * 16 + 8] = a1v;
        *(u16x8*)&Bs[nb][q * 8] = *(const u16x8*)&Bt[(size_t)nb * HID_F + k0 + q * 8];
        __syncthreads();

        short8 af0 = *(const short8*)&As[32 * wv + m16][quad * 8];
        short8 af1 = *(const short8*)&As[32 * wv + 16 + m16][quad * 8];
#pragma unroll
        for (int ct = 0; ct < 4; ct++) {
            short8 bf = *(const short8*)&Bs[16 * ct + m16][quad * 8];
            acc[0][ct] = __builtin_amdgcn_mfma_f32_16x16x32_bf16(af0, bf, acc[0][ct], 0, 0, 0);
            acc[1][ct] = __builtin_amdgcn_mfma_f32_16x16x32_bf16(af1, bf, acc[1][ct], 0, 0, 0);
        }
        __syncthreads();
    }
#pragma unroll
    for (int rt = 0; rt < 2; rt++)
#pragma unroll
        for (int r4 = 0; r4 < 4; r4++) {
            int grow = row0 + 32 * wv + 16 * rt + quad * 4 + r4;
            if (grow < N_NODES) {
                float dv = dinv[grow];
#pragma unroll
                for (int ct = 0; ct < 4; ct++)
                    C[(size_t)grow * OUT_FT + 16 * ct + m16] = f2bf(acc[rt][ct][r4] * dv);
            }
        }
}

// ---------------- aggregation (CSR gather-reduce, bf16 in / fp32 acc) ----------------

__global__ __launch_bounds__(256) void k_agg1(const u16* __restrict__ hs,
                                              const int* __restrict__ offsets,
                                              const int* __restrict__ csr,
                                              const float* __restrict__ dinv,
                                              const float* __restrict__ b,
                                              u16* __restrict__ out) {
    int wave = threadIdx.x >> 6;
    int lane = threadIdx.x & 63;
    int node = blockIdx.x * 4 + wave;
    if (node >= N_NODES) return;
    int beg = offsets[node], end = offsets[node + 1];
    float2 acc = __bfloat1622float2(*(const __hip_bfloat162*)&hs[(size_t)node * HID_F + lane * 2]);
    int j = beg;
    for (; j + 4 <= end; j += 4) {
        int s0 = csr[j], s1 = csr[j + 1], s2 = csr[j + 2], s3 = csr[j + 3];
        float2 v0 = __bfloat1622float2(*(const __hip_bfloat162*)&hs[(size_t)s0 * HID_F + lane * 2]);
        float2 v1 = __bfloat1622float2(*(const __hip_bfloat162*)&hs[(size_t)s1 * HID_F + lane * 2]);
        float2 v2 = __bfloat1622float2(*(const __hip_bfloat162*)&hs[(size_t)s2 * HID_F + lane * 2]);
        float2 v3 = __bfloat1622float2(*(const __hip_bfloat162*)&hs[(size_t)s3 * HID_F + lane * 2]);
        acc.x += v0.x + v1.x + v2.x + v3.x;
        acc.y += v0.y + v1.y + v2.y + v3.y;
    }
    for (; j < end; j++) {
        float2 v = __bfloat1622float2(*(const __hip_bfloat162*)&hs[(size_t)csr[j] * HID_F + lane * 2]);
        acc.x += v.x;
        acc.y += v.y;
    }
    float dv = dinv[node];
    float2 bb = *(const float2*)&b[lane * 2];
    float ox = fmaxf(dv * acc.x + bb.x, 0.f);
    float oy = fmaxf(dv * acc.y + bb.y, 0.f);
    __hip_bfloat162 ob = __float22bfloat162_rn(make_float2(ox, oy));
    *(__hip_bfloat162*)&out[(size_t)node * HID_F + lane * 2] = ob;
}

__global__ __launch_bounds__(256) void k_agg2(const u16* __restrict__ hs,
                                              const int* __restrict__ offsets,
                                              const int* __restrict__ csr,
                                              const float* __restrict__ dinv,
                                              const float* __restrict__ b,
                                              float* __restrict__ out) {
    int wave = threadIdx.x >> 6;
    int lane = threadIdx.x & 63;
    int node = blockIdx.x * 4 + wave;
    if (node >= N_NODES) return;
    int beg = offsets[node], end = offsets[node + 1];
    float acc = __bfloat162float(*(const __hip_bfloat16*)&hs[(size_t)node * OUT_FT + lane]);
    int j = beg;
    for (; j + 4 <= end; j += 4) {
        int s0 = csr[j], s1 = csr[j + 1], s2 = csr[j + 2], s3 = csr[j + 3];
        acc += __bfloat162float(*(const __hip_bfloat16*)&hs[(size_t)s0 * OUT_FT + lane]) +
               __bfloat162float(*(const __hip_bfloat16*)&hs[(size_t)s1 * OUT_FT + lane]) +
               __bfloat162float(*(const __hip_bfloat16*)&hs[(size_t)s2 * OUT_FT + lane]) +
               __bfloat162float(*(const __hip_bfloat16*)&hs[(size_t)s3 * OUT_FT + lane]);
    }
    for (; j < end; j++)
        acc += __bfloat162float(*(const __hip_bfloat16*)&hs[(size_t)csr[j] * OUT_FT + lane]);
    out[(size_t)node * OUT_FT + lane] = dinv[node] * acc + b[lane];
}

// ---------------- launch ----------------

extern "C" void kernel_launch(void* const* d_in, const int* in_sizes, int n_in,
                              void* d_out, int out_size, void* d_ws, size_t ws_size,
                              hipStream_t stream) {
    const float* x  = (const float*)d_in[0];
    const int*   ei = (const int*)d_in[1];  // [2][E]
    const float* W1 = (const float*)d_in[2];
    const float* b1 = (const float*)d_in[3];
    const float* W2 = (const float*)d_in[4];
    const float* b2 = (const float*)d_in[5];
    float* out = (float*)d_out;

    char* ws = (char*)d_ws;
    int*   counts  = (int*)(ws + 0);           // N ints
    int*   offsets = (int*)(ws + 400384);      // N+1 ints
    int*   fill    = (int*)(ws + 800896);      // N ints
    float* dinv    = (float*)(ws + 1201152);   // N floats
    int*   csr     = (int*)(ws + 1601536);     // E ints -> 8001536
    u16*   W1t     = (u16*)(ws + 8001536);     // 128x256 bf16 -> 8067072
    u16*   W2t     = (u16*)(ws + 8067072);     // 64x128 bf16  -> 8083456
    u16*   hs1     = (u16*)(ws + 8083456);     // N*128 bf16 -> 33683456
    u16*   a1      = (u16*)(ws + 33683456);    // N*128 bf16 -> 59283456
    u16*   hs2     = hs1;                      // reuse: hs1 dead after agg1
    int*   blksum  = (int*)(ws + 59283456);
    int*   blkoff  = (int*)(ws + 59283456 + 2048);

    const int* srcA = ei;
    const int* dstA = ei + N_EDGES;

    hipMemsetAsync(counts, 0, N_NODES * sizeof(int), stream);
    hipMemsetAsync(fill, 0, N_NODES * sizeof(int), stream);

    k_count<<<(N_EDGES + 255) / 256, 256, 0, stream>>>(dstA, counts);
    k_dinv<<<(N_NODES + 255) / 256, 256, 0, stream>>>(counts, dinv);
    k_blocksum<<<NBLK_SCAN, 256, 0, stream>>>(counts, blksum);
    k_scanblk<<<1, 512, 0, stream>>>(blksum, blkoff);
    k_offsets<<<NBLK_SCAN, 256, 0, stream>>>(counts, blkoff, offsets);
    k_fill<<<(N_EDGES + 255) / 256, 256, 0, stream>>>(srcA, dstA, offsets, fill, csr);

    k_castT<<<(IN_FEAT * HID_F + 255) / 256, 256, 0, stream>>>(W1, W1t, IN_FEAT, HID_F);
    k_castT<<<(HID_F * OUT_FT + 255) / 256, 256, 0, stream>>>(W2, W2t, HID_F, OUT_FT);

    int gblk = (N_NODES + 127) / 128;  // 782
    k_gemm1<<<gblk, 256, 0, stream>>>(x, W1t, dinv, hs1);
    k_agg1<<<(N_NODES + 3) / 4, 256, 0, stream>>>(hs1, offsets, csr, dinv, b1, a1);
    k_gemm2<<<gblk, 256, 0, stream>>>(a1, W2t, dinv, hs2);
    k_agg2<<<(N_NODES + 3) / 4, 256, 0, stream>>>(hs2, offsets, csr, dinv, b2, out);
}